// Round 8
// baseline (255.277 us; speedup 1.0000x reference)
//
#include <hip/hip_runtime.h>

typedef unsigned short u16;
typedef __attribute__((ext_vector_type(8))) __bf16 bf16x8;
typedef __attribute__((ext_vector_type(4))) float f32x4;
typedef __attribute__((ext_vector_type(4))) unsigned short u16x4;

#define AS1 __attribute__((address_space(1)))
#define AS3 __attribute__((address_space(3)))

// blob layout (u16 element offsets) -- bf16 copies of GEMM inputs
#define OB_X    0L
#define OB_H    4194304L
#define OB_WI   8388608L
#define OB_WF   10485760L
#define OB_WO   12582912L
#define OB_WXS  14680064L
#define OB_WXG  15728640L
#define OB_WHG  16777216L
#define BLOB_EL 17825792L

__device__ __forceinline__ u16 f2b(float f) {
    unsigned u = __float_as_uint(f);
    u += 0x7fffu + ((u >> 16) & 1u);   // round-to-nearest-even
    return (u16)(u >> 16);
}

// ---------------- f32 -> bf16 blob build (verified r6) ----------------
__global__ __launch_bounds__(256) void convert_all(
    const float* __restrict__ x, const float* __restrict__ h,
    const float* __restrict__ Wi, const float* __restrict__ Wf,
    const float* __restrict__ Wo, const float* __restrict__ Wxs,
    const float* __restrict__ Wxg, const float* __restrict__ Whg,
    u16* __restrict__ blob)
{
    long e = ((long)blockIdx.x * 256 + threadIdx.x) * 8;
    const float* src; long off;
    if      (e < OB_H)   { src = x;   off = e; }
    else if (e < OB_WI)  { src = h;   off = e - OB_H; }
    else if (e < OB_WF)  { src = Wi;  off = e - OB_WI; }
    else if (e < OB_WO)  { src = Wf;  off = e - OB_WF; }
    else if (e < OB_WXS) { src = Wo;  off = e - OB_WO; }
    else if (e < OB_WXG) { src = Wxs; off = e - OB_WXS; }
    else if (e < OB_WHG) { src = Wxg; off = e - OB_WXG; }
    else                 { src = Whg; off = e - OB_WHG; }
    f32x4 v0 = *(const f32x4*)(src + off);
    f32x4 v1 = *(const f32x4*)(src + off + 4);
    u16x4 o0, o1;
    o0.x = f2b(v0.x); o0.y = f2b(v0.y); o0.z = f2b(v0.z); o0.w = f2b(v0.w);
    o1.x = f2b(v1.x); o1.y = f2b(v1.y); o1.z = f2b(v1.z); o1.w = f2b(v1.w);
    *(u16x4*)(blob + e) = o0;
    *(u16x4*)(blob + e + 4) = o1;
}

__device__ __forceinline__ float sigf(float z) {
    return 1.f / (1.f + __expf(-z));
}

// ---------------- fully-fused SRU-LSTM cell: counted-vmcnt double buffer ----
// A/B vs round 1 (121us): IDENTICAL geometry (8 waves, 256m x 64j x 5seg,
// BK=64, dbuf 144KB, acc 160, read-ratio 0.36) -- ONLY the sync changed.
// r1 used __syncthreads() which drains vmcnt(0), killing the prefetch it just
// issued. Here each tile does: stage 9 loads (next buf) -> ONE asm
// {s_waitcnt vmcnt(9); s_barrier} (waits ONLY the previous tile's 9 loads,
// issued a full compute-phase ago => ~free; the new 9 stay in flight across
// the barrier) -> plain-C++ compute (compiler owns lgkmcnt) -> raw s_barrier.
// No sched_barrier spam (r3's spill cause), no setprio (null on 2-phase,
// m230), uniform 9 loads/tile (dummy seg4/tail stages keep vmcnt exact),
// final vmcnt(0) so no load is in flight at block exit (LDS realloc hazard).
__global__ __launch_bounds__(512) void srulstm_fused(
    const u16* __restrict__ blob,
    const float* __restrict__ c_prev,
    const float* __restrict__ bi, const float* __restrict__ bfv,
    const float* __restrict__ bo, const float* __restrict__ bxs,
    const float* __restrict__ bxg, const float* __restrict__ bhg,
    float* __restrict__ out)
{
    __shared__ __align__(16) u16 As[2][256 * 64];       // 2 x 32 KB
    __shared__ __align__(16) u16 Bs[2][5 * 64 * 64];    // 2 x 40 KB  (=144 KB)

    const u16* x = blob + OB_X;
    const u16* h = blob + OB_H;

    const int t = threadIdx.x;
    const int j0 = blockIdx.x * 64;    // 16 j-slices
    const int m0 = blockIdx.y * 256;   // 16 m-tiles  (grid 16x16 = 256 = 1/CU)

    const u16* w0   = blob + OB_WI  + j0 * 2048;
    const u16* w1   = blob + OB_WF  + j0 * 2048;
    const u16* w2   = blob + OB_WO  + j0 * 2048;
    const u16* w3lo = blob + OB_WXG + j0 * 1024;
    const u16* w3hi = blob + OB_WHG + j0 * 1024;
    const u16* w4   = blob + OB_WXS + j0 * 1024;

    const u16* aLo = x + m0 * 1024;
    const u16* aHi = h + m0 * 1024;

    const int lane = t & 63;
    const int wave = t >> 6;           // 0..7
    const int wm = (wave >> 1) << 6;   // 0/64/128/192
    const int wn = (wave & 1) << 5;    // 0/32
    const int fr = lane & 15;
    const int fq = lane >> 4;
    const int r7 = fr & 7;

    const int er = t >> 3;             // staging row in 64-row chunk (0..63)
    const int gsw = (((t & 7) ^ (er & 7)) << 3);

    f32x4 acc[5][4][2] = {};           // [seg][mi][ni]

    // ---- staging: uniform 9 global_load_lds per tile ----
    auto stage = [&](u16* An, u16* Bn, int kS) {
        const int kSc = (kS < 2048) ? kS : 1984;    // tail: dummy re-stage
        const u16* aSrc = ((kSc < 1024) ? aLo : aHi) + (kSc & 1023);
#pragma unroll
        for (int it = 0; it < 4; ++it)
            __builtin_amdgcn_global_load_lds(
                (AS1 void*)(aSrc + (it * 64 + er) * 1024 + gsw),
                (AS3 void*)(An + (it * 512 + t) * 8), 16, 0, 0);
        __builtin_amdgcn_global_load_lds((AS1 void*)(w0 + kSc + er * 2048 + gsw),
            (AS3 void*)(Bn + t * 8), 16, 0, 0);
        __builtin_amdgcn_global_load_lds((AS1 void*)(w1 + kSc + er * 2048 + gsw),
            (AS3 void*)(Bn + 4096 + t * 8), 16, 0, 0);
        __builtin_amdgcn_global_load_lds((AS1 void*)(w2 + kSc + er * 2048 + gsw),
            (AS3 void*)(Bn + 8192 + t * 8), 16, 0, 0);
        const u16* w3 = (kSc < 1024) ? (w3lo + kSc) : (w3hi + (kSc - 1024));
        __builtin_amdgcn_global_load_lds((AS1 void*)(w3 + er * 1024 + gsw),
            (AS3 void*)(Bn + 12288 + t * 8), 16, 0, 0);
        // seg4 read only when k0<1024; dummy (in-bounds) stage otherwise
        __builtin_amdgcn_global_load_lds((AS1 void*)(w4 + (kSc & 1023) + er * 1024 + gsw),
            (AS3 void*)(Bn + 16384 + t * 8), 16, 0, 0);
    };

    // ---- compute one BK=64 tile from LDS (r1-verified fragment math) ----
    auto compute = [&](const u16* Ac, const u16* Bc, bool seg4) {
#pragma unroll
        for (int kk = 0; kk < 64; kk += 32) {
            const int sw = ((((kk >> 3) + fq) ^ r7) << 3);
            bf16x8 a[4];
#pragma unroll
            for (int mi = 0; mi < 4; ++mi)
                a[mi] = *(const bf16x8*)(Ac + (wm + mi * 16 + fr) * 64 + sw);
#pragma unroll
            for (int s = 0; s < 4; ++s) {
                bf16x8 b0 = *(const bf16x8*)(Bc + s * 4096 + (wn + fr) * 64 + sw);
                bf16x8 b1 = *(const bf16x8*)(Bc + s * 4096 + (wn + 16 + fr) * 64 + sw);
#pragma unroll
                for (int mi = 0; mi < 4; ++mi) {
                    acc[s][mi][0] = __builtin_amdgcn_mfma_f32_16x16x32_bf16(
                        a[mi], b0, acc[s][mi][0], 0, 0, 0);
                    acc[s][mi][1] = __builtin_amdgcn_mfma_f32_16x16x32_bf16(
                        a[mi], b1, acc[s][mi][1], 0, 0, 0);
                }
            }
            if (seg4) {
                bf16x8 b0 = *(const bf16x8*)(Bc + 16384 + (wn + fr) * 64 + sw);
                bf16x8 b1 = *(const bf16x8*)(Bc + 16384 + (wn + 16 + fr) * 64 + sw);
#pragma unroll
                for (int mi = 0; mi < 4; ++mi) {
                    acc[4][mi][0] = __builtin_amdgcn_mfma_f32_16x16x32_bf16(
                        a[mi], b0, acc[4][mi][0], 0, 0, 0);
                    acc[4][mi][1] = __builtin_amdgcn_mfma_f32_16x16x32_bf16(
                        a[mi], b1, acc[4][mi][1], 0, 0, 0);
                }
            }
        }
    };

    // prologue: fill buffer 0 (9 loads in flight)
    stage(As[0], Bs[0], 0);

    // main loop: 32 tiles, unrolled x2 for static buffer indices
    for (int k0 = 0; k0 < 2048; k0 += 128) {
        // tile A: compute buf0, prefetch k0+64 into buf1
        stage(As[1], Bs[1], k0 + 64);
        asm volatile("s_waitcnt vmcnt(9)\n\ts_barrier" ::: "memory");
        compute(As[0], Bs[0], k0 < 1024);
        asm volatile("s_barrier" ::: "memory");
        // tile B: compute buf1, prefetch k0+128 into buf0
        stage(As[0], Bs[0], k0 + 128);
        asm volatile("s_waitcnt vmcnt(9)\n\ts_barrier" ::: "memory");
        compute(As[1], Bs[1], (k0 + 64) < 1024);
        asm volatile("s_barrier" ::: "memory");
    }
    // drain the final dummy stage: no load may be in flight at block exit
    asm volatile("s_waitcnt vmcnt(0)" ::: "memory");

    // ---- in-register LSTM epilogue (r1-verified) ----
    // C/D layout (m89): lane holds D[m=fq*4+r][n=fr]; all 5 segs aligned.
    const int orow = m0 + wm + (fq << 2);
    const int ocol = j0 + wn + fr;
#pragma unroll
    for (int ni = 0; ni < 2; ++ni) {
        const int col = ocol + ni * 16;
        const float bi_v = bi[col],  bf_v = bfv[col], bo_v = bo[col];
        const float bs_v = bxs[col], bg_v = bxg[col], bh_v = bhg[col];
#pragma unroll
        for (int mi = 0; mi < 4; ++mi) {
#pragma unroll
            for (int r = 0; r < 4; ++r) {
                const long idx = (long)(orow + mi * 16 + r) * 1024 + col;
                const float cp = c_prev[idx];
                const float i_t = sigf(acc[0][mi][ni][r] + bi_v);
                const float f_t = sigf(acc[1][mi][ni][r] + bf_v);
                const float o_t = sigf(acc[2][mi][ni][r] + bo_v);
                const float cand = acc[3][mi][ni][r] + bg_v + bh_v;
                const float s_t  = acc[4][mi][ni][r] + bs_v;
                const float g_t = tanhf(s_t * cand);
                const float c_t = f_t * cp + i_t * g_t;
                const float h_t = o_t * tanhf(c_t);
                out[idx] = h_t;                    // h_t
                out[4194304L + idx] = c_t;         // c_t
            }
        }
    }
}

extern "C" void kernel_launch(void* const* d_in, const int* in_sizes, int n_in,
                              void* d_out, int out_size, void* d_ws, size_t ws_size,
                              hipStream_t stream)
{
    u16* blob = (u16*)d_ws;            // 35.7 MB
    float* out = (float*)d_out;

    const long convBlocks = BLOB_EL / 8 / 256;     // 8704

    convert_all<<<dim3(convBlocks), dim3(256), 0, stream>>>(
        (const float*)d_in[0], (const float*)d_in[1], (const float*)d_in[3],
        (const float*)d_in[5], (const float*)d_in[7], (const float*)d_in[9],
        (const float*)d_in[11], (const float*)d_in[13], blob);

    srulstm_fused<<<dim3(16, 16), dim3(512), 0, stream>>>(
        blob, (const float*)d_in[2], (const float*)d_in[4], (const float*)d_in[6],
        (const float*)d_in[8], (const float*)d_in[10], (const float*)d_in[12],
        (const float*)d_in[14], out);
}

// Round 9
// 241.576 us; speedup vs baseline: 1.0567x; 1.0567x over previous
//
#include <hip/hip_runtime.h>

typedef unsigned short u16;
typedef __attribute__((ext_vector_type(8))) __bf16 bf16x8;
typedef __attribute__((ext_vector_type(4))) float f32x4;
typedef __attribute__((ext_vector_type(4))) unsigned short u16x4;

#define AS1 __attribute__((address_space(1)))
#define AS3 __attribute__((address_space(3)))

// blob layout (u16 element offsets) -- bf16 copies of GEMM inputs
#define OB_X    0L
#define OB_H    4194304L
#define OB_WI   8388608L
#define OB_WF   10485760L
#define OB_WO   12582912L
#define OB_WXS  14680064L
#define OB_WXG  15728640L
#define OB_WHG  16777216L
#define BLOB_EL 17825792L

__device__ __forceinline__ u16 f2b(float f) {
    unsigned u = __float_as_uint(f);
    u += 0x7fffu + ((u >> 16) & 1u);   // round-to-nearest-even
    return (u16)(u >> 16);
}

// ---------------- f32 -> bf16 blob build (verified r6) ----------------
__global__ __launch_bounds__(256) void convert_all(
    const float* __restrict__ x, const float* __restrict__ h,
    const float* __restrict__ Wi, const float* __restrict__ Wf,
    const float* __restrict__ Wo, const float* __restrict__ Wxs,
    const float* __restrict__ Wxg, const float* __restrict__ Whg,
    u16* __restrict__ blob)
{
    long e = ((long)blockIdx.x * 256 + threadIdx.x) * 8;
    const float* src; long off;
    if      (e < OB_H)   { src = x;   off = e; }
    else if (e < OB_WI)  { src = h;   off = e - OB_H; }
    else if (e < OB_WF)  { src = Wi;  off = e - OB_WI; }
    else if (e < OB_WO)  { src = Wf;  off = e - OB_WF; }
    else if (e < OB_WXS) { src = Wo;  off = e - OB_WO; }
    else if (e < OB_WXG) { src = Wxs; off = e - OB_WXS; }
    else if (e < OB_WHG) { src = Wxg; off = e - OB_WXG; }
    else                 { src = Whg; off = e - OB_WHG; }
    f32x4 v0 = *(const f32x4*)(src + off);
    f32x4 v1 = *(const f32x4*)(src + off + 4);
    u16x4 o0, o1;
    o0.x = f2b(v0.x); o0.y = f2b(v0.y); o0.z = f2b(v0.z); o0.w = f2b(v0.w);
    o1.x = f2b(v1.x); o1.y = f2b(v1.y); o1.z = f2b(v1.z); o1.w = f2b(v1.w);
    *(u16x4*)(blob + e) = o0;
    *(u16x4*)(blob + e + 4) = o1;
}

__device__ __forceinline__ float sigf(float z) {
    return 1.f / (1.f + __expf(-z));
}

#define WAITBAR2 asm volatile("s_waitcnt vmcnt(2)\n\ts_barrier" ::: "memory")
#define BARRIER  asm volatile("s_barrier" ::: "memory")

// ---------------- fully-fused SRU-LSTM cell: 4-phase fine interleave ----------
// r7 geometry (8 waves, 128m x 64j x 5seg, per-wave 32x32, acc 80 -- best
// bench total 222us, zero spill) + the m201 phase discipline that the regime
// gate says is REQUIRED for T4/T5 to pay (r8 proved coarse 2-phase counted
// vmcnt is null; m233: lockstep 2-phase = sum-of-pipes).
// Per K-tile, 4 phases; each: {vmcnt(2)+bar -> ds_read subtile -> issue 1-2
// gload_lds (next tile, consumption order A0,A1,B0..B4) -> prio1 MFMA prio0}.
// Waits never reach 0 in the loop; 7 loads/tile uniform (dummy tail stage);
// vmcnt(0) once before epilogue. No sched_barrier (r3 spill), no lgkmcnt asm
// (plain-C++ ds_reads carry the true dependency into the MFMAs).
__global__ __launch_bounds__(512) void srulstm_fused(
    const u16* __restrict__ blob,
    const float* __restrict__ c_prev,
    const float* __restrict__ bi, const float* __restrict__ bfv,
    const float* __restrict__ bo, const float* __restrict__ bxs,
    const float* __restrict__ bxg, const float* __restrict__ bhg,
    float* __restrict__ out)
{
    __shared__ __align__(16) u16 As[2][128 * 64];    // 2 x 16 KB
    __shared__ __align__(16) u16 Bs[2][5 * 64 * 64]; // 2 x 40 KB  (112 KB tot)

    const u16* x = blob + OB_X;
    const u16* h = blob + OB_H;

    const int t = threadIdx.x;
    const int j0 = blockIdx.x * 64;    // 16 j-slices
    const int m0 = blockIdx.y * 128;   // 32 m-tiles

    const u16* w0   = blob + OB_WI  + j0 * 2048;
    const u16* w1   = blob + OB_WF  + j0 * 2048;
    const u16* w2   = blob + OB_WO  + j0 * 2048;
    const u16* w3lo = blob + OB_WXG + j0 * 1024;
    const u16* w3hi = blob + OB_WHG + j0 * 1024;
    const u16* w4   = blob + OB_WXS + j0 * 1024;

    const u16* aLo = x + m0 * 1024;
    const u16* aHi = h + m0 * 1024;

    const int lane = t & 63;
    const int wave = t >> 6;           // 0..7
    const int wm = (wave >> 1) << 5;   // 0/32/64/96
    const int wn = (wave & 1) << 5;    // 0/32
    const int fr = lane & 15;
    const int fq = lane >> 4;
    const int r7 = fr & 7;

    const int er = t >> 3;             // staging row in 64-row chunk (0..63)
    const int gsw = (((t & 7) ^ (er & 7)) << 3);

    f32x4 acc[5][2][2] = {};           // [seg][mi][ni] -- 80 f32/thread

    // ---- stage pieces (issue order matters for vmcnt accounting) ----
    auto stA = [&](u16* An, int kSc) {             // 2 gloads: A0,A1
        const u16* aSrc = ((kSc < 1024) ? aLo : aHi) + (kSc & 1023);
#pragma unroll
        for (int it = 0; it < 2; ++it)
            __builtin_amdgcn_global_load_lds(
                (AS1 void*)(aSrc + (it * 64 + er) * 1024 + gsw),
                (AS3 void*)(An + (it * 512 + t) * 8), 16, 0, 0);
    };
    auto stB = [&](u16* dst, const u16* src, int ld) {   // 1 gload
        __builtin_amdgcn_global_load_lds(
            (AS1 void*)(src + er * ld + gsw),
            (AS3 void*)(dst + t * 8), 16, 0, 0);
    };

    // ---- one K-tile, 4 phases ----
    auto tile = [&](const u16* Ac, const u16* Bc, u16* An, u16* Bn,
                    int k0, int kS) {
        const bool s4 = (k0 < 1024);
        const int kSc = (kS < 2048) ? kS : 1984;   // tail: dummy re-stage
        const u16* w3s = (kSc < 1024) ? (w3lo + kSc) : (w3hi + (kSc - 1024));
        const int sw0 = ((fq ^ r7) << 3);          // kk=0
        const int sw1 = (((4 + fq) ^ r7) << 3);    // kk=32

        // ---- ph1: A kk0 + segs0-2 kk0 (12 MFMA) ; stage A0,A1 ----
        WAITBAR2;
        {
            bf16x8 a0 = *(const bf16x8*)(Ac + (wm + fr) * 64 + sw0);
            bf16x8 a1 = *(const bf16x8*)(Ac + (wm + 16 + fr) * 64 + sw0);
            bf16x8 b00 = *(const bf16x8*)(Bc +         (wn + fr) * 64 + sw0);
            bf16x8 b01 = *(const bf16x8*)(Bc +         (wn + 16 + fr) * 64 + sw0);
            bf16x8 b10 = *(const bf16x8*)(Bc + 4096  + (wn + fr) * 64 + sw0);
            bf16x8 b11 = *(const bf16x8*)(Bc + 4096  + (wn + 16 + fr) * 64 + sw0);
            bf16x8 b20 = *(const bf16x8*)(Bc + 8192  + (wn + fr) * 64 + sw0);
            bf16x8 b21 = *(const bf16x8*)(Bc + 8192  + (wn + 16 + fr) * 64 + sw0);
            stA(An, kSc);
            __builtin_amdgcn_s_setprio(1);
            acc[0][0][0] = __builtin_amdgcn_mfma_f32_16x16x32_bf16(a0, b00, acc[0][0][0], 0, 0, 0);
            acc[0][0][1] = __builtin_amdgcn_mfma_f32_16x16x32_bf16(a0, b01, acc[0][0][1], 0, 0, 0);
            acc[0][1][0] = __builtin_amdgcn_mfma_f32_16x16x32_bf16(a1, b00, acc[0][1][0], 0, 0, 0);
            acc[0][1][1] = __builtin_amdgcn_mfma_f32_16x16x32_bf16(a1, b01, acc[0][1][1], 0, 0, 0);
            acc[1][0][0] = __builtin_amdgcn_mfma_f32_16x16x32_bf16(a0, b10, acc[1][0][0], 0, 0, 0);
            acc[1][0][1] = __builtin_amdgcn_mfma_f32_16x16x32_bf16(a0, b11, acc[1][0][1], 0, 0, 0);
            acc[1][1][0] = __builtin_amdgcn_mfma_f32_16x16x32_bf16(a1, b10, acc[1][1][0], 0, 0, 0);
            acc[1][1][1] = __builtin_amdgcn_mfma_f32_16x16x32_bf16(a1, b11, acc[1][1][1], 0, 0, 0);
            acc[2][0][0] = __builtin_amdgcn_mfma_f32_16x16x32_bf16(a0, b20, acc[2][0][0], 0, 0, 0);
            acc[2][0][1] = __builtin_amdgcn_mfma_f32_16x16x32_bf16(a0, b21, acc[2][0][1], 0, 0, 0);
            acc[2][1][0] = __builtin_amdgcn_mfma_f32_16x16x32_bf16(a1, b20, acc[2][1][0], 0, 0, 0);
            acc[2][1][1] = __builtin_amdgcn_mfma_f32_16x16x32_bf16(a1, b21, acc[2][1][1], 0, 0, 0);
            __builtin_amdgcn_s_setprio(0);

            // ---- ph2: segs3,4 kk0 (4-8 MFMA) ; stage B0,B1 ----
            WAITBAR2;
            bf16x8 b30 = *(const bf16x8*)(Bc + 12288 + (wn + fr) * 64 + sw0);
            bf16x8 b31 = *(const bf16x8*)(Bc + 12288 + (wn + 16 + fr) * 64 + sw0);
            stB(Bn, w0 + kSc, 2048);
            stB(Bn + 4096, w1 + kSc, 2048);
            __builtin_amdgcn_s_setprio(1);
            acc[3][0][0] = __builtin_amdgcn_mfma_f32_16x16x32_bf16(a0, b30, acc[3][0][0], 0, 0, 0);
            acc[3][0][1] = __builtin_amdgcn_mfma_f32_16x16x32_bf16(a0, b31, acc[3][0][1], 0, 0, 0);
            acc[3][1][0] = __builtin_amdgcn_mfma_f32_16x16x32_bf16(a1, b30, acc[3][1][0], 0, 0, 0);
            acc[3][1][1] = __builtin_amdgcn_mfma_f32_16x16x32_bf16(a1, b31, acc[3][1][1], 0, 0, 0);
            __builtin_amdgcn_s_setprio(0);
            if (s4) {
                bf16x8 b40 = *(const bf16x8*)(Bc + 16384 + (wn + fr) * 64 + sw0);
                bf16x8 b41 = *(const bf16x8*)(Bc + 16384 + (wn + 16 + fr) * 64 + sw0);
                __builtin_amdgcn_s_setprio(1);
                acc[4][0][0] = __builtin_amdgcn_mfma_f32_16x16x32_bf16(a0, b40, acc[4][0][0], 0, 0, 0);
                acc[4][0][1] = __builtin_amdgcn_mfma_f32_16x16x32_bf16(a0, b41, acc[4][0][1], 0, 0, 0);
                acc[4][1][0] = __builtin_amdgcn_mfma_f32_16x16x32_bf16(a1, b40, acc[4][1][0], 0, 0, 0);
                acc[4][1][1] = __builtin_amdgcn_mfma_f32_16x16x32_bf16(a1, b41, acc[4][1][1], 0, 0, 0);
                __builtin_amdgcn_s_setprio(0);
            }
        }

        // ---- ph3: A kk32 + segs0-2 kk32 (12 MFMA) ; stage B2,B3 ----
        BARRIER;
        {
            bf16x8 a0 = *(const bf16x8*)(Ac + (wm + fr) * 64 + sw1);
            bf16x8 a1 = *(const bf16x8*)(Ac + (wm + 16 + fr) * 64 + sw1);
            bf16x8 b00 = *(const bf16x8*)(Bc +         (wn + fr) * 64 + sw1);
            bf16x8 b01 = *(const bf16x8*)(Bc +         (wn + 16 + fr) * 64 + sw1);
            bf16x8 b10 = *(const bf16x8*)(Bc + 4096  + (wn + fr) * 64 + sw1);
            bf16x8 b11 = *(const bf16x8*)(Bc + 4096  + (wn + 16 + fr) * 64 + sw1);
            bf16x8 b20 = *(const bf16x8*)(Bc + 8192  + (wn + fr) * 64 + sw1);
            bf16x8 b21 = *(const bf16x8*)(Bc + 8192  + (wn + 16 + fr) * 64 + sw1);
            stB(Bn + 8192, w2 + kSc, 2048);
            stB(Bn + 12288, w3s, 1024);
            __builtin_amdgcn_s_setprio(1);
            acc[0][0][0] = __builtin_amdgcn_mfma_f32_16x16x32_bf16(a0, b00, acc[0][0][0], 0, 0, 0);
            acc[0][0][1] = __builtin_amdgcn_mfma_f32_16x16x32_bf16(a0, b01, acc[0][0][1], 0, 0, 0);
            acc[0][1][0] = __builtin_amdgcn_mfma_f32_16x16x32_bf16(a1, b00, acc[0][1][0], 0, 0, 0);
            acc[0][1][1] = __builtin_amdgcn_mfma_f32_16x16x32_bf16(a1, b01, acc[0][1][1], 0, 0, 0);
            acc[1][0][0] = __builtin_amdgcn_mfma_f32_16x16x32_bf16(a0, b10, acc[1][0][0], 0, 0, 0);
            acc[1][0][1] = __builtin_amdgcn_mfma_f32_16x16x32_bf16(a0, b11, acc[1][0][1], 0, 0, 0);
            acc[1][1][0] = __builtin_amdgcn_mfma_f32_16x16x32_bf16(a1, b10, acc[1][1][0], 0, 0, 0);
            acc[1][1][1] = __builtin_amdgcn_mfma_f32_16x16x32_bf16(a1, b11, acc[1][1][1], 0, 0, 0);
            acc[2][0][0] = __builtin_amdgcn_mfma_f32_16x16x32_bf16(a0, b20, acc[2][0][0], 0, 0, 0);
            acc[2][0][1] = __builtin_amdgcn_mfma_f32_16x16x32_bf16(a0, b21, acc[2][0][1], 0, 0, 0);
            acc[2][1][0] = __builtin_amdgcn_mfma_f32_16x16x32_bf16(a1, b20, acc[2][1][0], 0, 0, 0);
            acc[2][1][1] = __builtin_amdgcn_mfma_f32_16x16x32_bf16(a1, b21, acc[2][1][1], 0, 0, 0);
            __builtin_amdgcn_s_setprio(0);

            // ---- ph4: segs3,4 kk32 (4-8 MFMA) ; stage B4 ----
            BARRIER;
            bf16x8 b30 = *(const bf16x8*)(Bc + 12288 + (wn + fr) * 64 + sw1);
            bf16x8 b31 = *(const bf16x8*)(Bc + 12288 + (wn + 16 + fr) * 64 + sw1);
            stB(Bn + 16384, w4 + (kSc & 1023), 1024);
            __builtin_amdgcn_s_setprio(1);
            acc[3][0][0] = __builtin_amdgcn_mfma_f32_16x16x32_bf16(a0, b30, acc[3][0][0], 0, 0, 0);
            acc[3][0][1] = __builtin_amdgcn_mfma_f32_16x16x32_bf16(a0, b31, acc[3][0][1], 0, 0, 0);
            acc[3][1][0] = __builtin_amdgcn_mfma_f32_16x16x32_bf16(a1, b30, acc[3][1][0], 0, 0, 0);
            acc[3][1][1] = __builtin_amdgcn_mfma_f32_16x16x32_bf16(a1, b31, acc[3][1][1], 0, 0, 0);
            __builtin_amdgcn_s_setprio(0);
            if (s4) {
                bf16x8 b40 = *(const bf16x8*)(Bc + 16384 + (wn + fr) * 64 + sw1);
                bf16x8 b41 = *(const bf16x8*)(Bc + 16384 + (wn + 16 + fr) * 64 + sw1);
                __builtin_amdgcn_s_setprio(1);
                acc[4][0][0] = __builtin_amdgcn_mfma_f32_16x16x32_bf16(a0, b40, acc[4][0][0], 0, 0, 0);
                acc[4][0][1] = __builtin_amdgcn_mfma_f32_16x16x32_bf16(a0, b41, acc[4][0][1], 0, 0, 0);
                acc[4][1][0] = __builtin_amdgcn_mfma_f32_16x16x32_bf16(a1, b40, acc[4][1][0], 0, 0, 0);
                acc[4][1][1] = __builtin_amdgcn_mfma_f32_16x16x32_bf16(a1, b41, acc[4][1][1], 0, 0, 0);
                __builtin_amdgcn_s_setprio(0);
            }
        }
    };

    // prologue: fill buffer 0 in consumption order (7 loads in flight)
    stA(As[0], 0);
    stB(Bs[0],         w0,   2048);
    stB(Bs[0] + 4096,  w1,   2048);
    stB(Bs[0] + 8192,  w2,   2048);
    stB(Bs[0] + 12288, w3lo, 1024);
    stB(Bs[0] + 16384, w4,   1024);

    for (int k0 = 0; k0 < 2048; k0 += 128) {
        tile(As[0], Bs[0], As[1], Bs[1], k0,      k0 + 64);
        tile(As[1], Bs[1], As[0], Bs[0], k0 + 64, k0 + 128);
    }
    // drain the final dummy stage before LDS lifetime ends
    asm volatile("s_waitcnt vmcnt(0)" ::: "memory");

    // ---- in-register LSTM epilogue (r7-verified) ----
    // C/D layout (m89): lane holds D[m=fq*4+r][n=fr]; all 5 segs aligned.
    const int orow = m0 + wm + (fq << 2);
    const int ocol = j0 + wn + fr;
#pragma unroll
    for (int ni = 0; ni < 2; ++ni) {
        const int col = ocol + ni * 16;
        const float bi_v = bi[col],  bf_v = bfv[col], bo_v = bo[col];
        const float bs_v = bxs[col], bg_v = bxg[col], bh_v = bhg[col];
#pragma unroll
        for (int mi = 0; mi < 2; ++mi) {
#pragma unroll
            for (int r = 0; r < 4; ++r) {
                const long idx = (long)(orow + mi * 16 + r) * 1024 + col;
                const float cp = c_prev[idx];
                const float i_t = sigf(acc[0][mi][ni][r] + bi_v);
                const float f_t = sigf(acc[1][mi][ni][r] + bf_v);
                const float o_t = sigf(acc[2][mi][ni][r] + bo_v);
                const float cand = acc[3][mi][ni][r] + bg_v + bh_v;
                const float s_t  = acc[4][mi][ni][r] + bs_v;
                const float g_t = tanhf(s_t * cand);
                const float c_t = f_t * cp + i_t * g_t;
                const float h_t = o_t * tanhf(c_t);
                out[idx] = h_t;                    // h_t
                out[4194304L + idx] = c_t;         // c_t
            }
        }
    }
}

extern "C" void kernel_launch(void* const* d_in, const int* in_sizes, int n_in,
                              void* d_out, int out_size, void* d_ws, size_t ws_size,
                              hipStream_t stream)
{
    u16* blob = (u16*)d_ws;            // 35.7 MB
    float* out = (float*)d_out;

    const long convBlocks = BLOB_EL / 8 / 256;     // 8704

    convert_all<<<dim3(convBlocks), dim3(256), 0, stream>>>(
        (const float*)d_in[0], (const float*)d_in[1], (const float*)d_in[3],
        (const float*)d_in[5], (const float*)d_in[7], (const float*)d_in[9],
        (const float*)d_in[11], (const float*)d_in[13], blob);

    srulstm_fused<<<dim3(16, 32), dim3(512), 0, stream>>>(
        blob, (const float*)d_in[2], (const float*)d_in[4], (const float*)d_in[6],
        (const float*)d_in[8], (const float*)d_in[10], (const float*)d_in[12],
        (const float*)d_in[14], out);
}